// Round 6
// baseline (1660.654 us; speedup 1.0000x reference)
//
#include <hip/hip_runtime.h>

// SlotAttention MI355X (gfx950), round 12: 4 dispatches, NO grid barrier.
// R9-R11 post-mortem: persistent kernel never executed in this harness
// (bit-identical absmax = max|ref| on zeroed output across 3 different
// binaries = deterministic non-launch). Abandoned.
// This round keeps the dispatch-reduction theory with safe machinery:
//  - k_pre (224 blocks): zero part/csp/cnt, slots init, per-block Mt (block 0
//    stores Mt to global), q0. (fuses old k_init + first k_gru)
//  - k_step x3 (2048 blocks = (b,cx)): R8 attn body; partials atomicAdd;
//    per-batch ticket counter; LAST chunk-block of batch b runs the GRU+MLP+q
//    tail for b in-block (atomicExch read-and-zero re-arms accumulators).
//    Last-block pattern needs no co-residency and no dispatch-order promise.
// Cross-dispatch data via normal kernel-boundary ordering. No memset needed.

#define Nn 4096
#define NCH 16

typedef _Float16 f16;
typedef _Float16 f16x8 __attribute__((ext_vector_type(8)));
typedef _Float16 f16x4 __attribute__((ext_vector_type(4)));
typedef float    f32x4 __attribute__((ext_vector_type(4)));

#define MFMA16(a,b,c) __builtin_amdgcn_mfma_f32_16x16x16f16(a,b,c,0,0,0)
#define MFMA32(a,b,c) __builtin_amdgcn_mfma_f32_16x16x32_f16(a,b,c,0,0,0)
#define LGKM0() asm volatile("s_waitcnt lgkmcnt(0)" ::: "memory")

#if __has_builtin(__builtin_amdgcn_rcpf)
#define RCPF(x) __builtin_amdgcn_rcpf(x)
#else
#define RCPF(x) (1.0f/(x))
#endif

static __device__ __forceinline__ float dot4(f32x4 a, f32x4 b) {
  return a.x*b.x + a.y*b.y + a.z*b.z + a.w*b.w;
}

static __device__ __forceinline__ void stageN(
    float (*dst)[68], const float* __restrict__ src, int stride, int sr, int sc)
{
  #pragma unroll
  for (int k = 0; k < 4; k++)
    *(f32x4*)&dst[sr][sc + k*4] = *(const f32x4*)(src + (size_t)sr*stride + sc + k*4);
}

// R7-proven: barrier, stage 64x64 chunk coalesced, barrier.
static __device__ __forceinline__ void stage_chunk(
    float (*Wl)[68], const float* __restrict__ src, int stride, int t)
{
  __syncthreads();                 // protect previous consumers of Wl
  int r = t >> 2, c4 = (t & 3) * 16;
  #pragma unroll
  for (int k = 0; k < 4; k++)
    *(f32x4*)&Wl[r][c4 + k*4] = *(const f32x4*)(src + (size_t)r*stride + c4 + k*4);
  __syncthreads();
}

static __device__ __forceinline__ float dot_row(
    const float (*Wl)[68], int d, const float* v)
{
  float a0 = 0.f, a1 = 0.f;
  #pragma unroll
  for (int jc = 0; jc < 16; jc += 2) {
    a0 += dot4(*(const f32x4*)&Wl[d][jc*4],     *(const f32x4*)(v + jc*4));
    a1 += dot4(*(const f32x4*)&Wl[d][jc*4 + 4], *(const f32x4*)(v + jc*4 + 4));
  }
  return a0 + a1;
}

static __device__ __forceinline__ void tile_common(
    f16x8 xf0, f16x8 xf1, const f16x8* qkB, float beta,
    f16x8 selLo, f16x8 selHi, bool valid, f32x4* acc, float& csump)
{
  const f32x4 zero4 = {0.f,0.f,0.f,0.f};
  f32x4 lg = zero4;
  lg = MFMA32(xf0, qkB[0], lg);
  lg = MFMA32(xf1, qkB[1], lg);
  float e[4], sm[4];
  #pragma unroll
  for (int j = 0; j < 4; j++) {
    float L = lg[j] + beta;
    e[j] = valid ? __expf(L) : 0.f;
    sm[j] = e[j];
  }
  #pragma unroll
  for (int m = 1; m < 16; m <<= 1)
    #pragma unroll
    for (int j = 0; j < 4; j++) sm[j] += __shfl_xor(sm[j], m, 64);
  f16x4 pp;
  #pragma unroll
  for (int j = 0; j < 4; j++) {
    float p = valid ? (e[j]*RCPF(sm[j]) + 1e-8f) : 0.f;
    csump += p;
    pp[j] = (f16)p;
  }
  #pragma unroll
  for (int nb = 0; nb < 4; nb++) {
    f32x4 tr = MFMA32(nb < 2 ? xf0 : xf1, (nb & 1) ? selHi : selLo, zero4);
    f16x4 xt; xt.x=(f16)tr.x; xt.y=(f16)tr.y; xt.z=(f16)tr.z; xt.w=(f16)tr.w;
    acc[nb] = MFMA16(pp, xt, acc[nb]);
  }
}

// ----------------------------------------------------------------- k_pre ----
// 224 blocks x 256. Zero accumulators; per-block Mt (block0 -> global);
// slots init (wave = row); q0 -> qkpad/qkaux.
__global__ __launch_bounds__(256) void k_pre(
    const float* __restrict__ noise, const float* __restrict__ mu,
    const float* __restrict__ ls, const float* __restrict__ Wq,
    const float* __restrict__ Wk,
    const float* __restrict__ lnw_in, const float* __restrict__ lnb_in,
    const float* __restrict__ lns_w, const float* __restrict__ lns_b,
    float* __restrict__ slots, f16* __restrict__ qkpad,
    float* __restrict__ qkaux, float* __restrict__ Mtg,
    float* __restrict__ part, float* __restrict__ csp,
    unsigned* __restrict__ cnt)
{
  __shared__ __align__(16) float Wl[64][68];
  __shared__ __align__(16) float Mt_l[64][68];
  __shared__ __align__(16) float sn2[4][64];
  const int bid = blockIdx.x, tid = threadIdx.x;
  const int w = tid >> 6, lane = tid & 63;
  const int sr = tid >> 2, sc = (tid & 3) * 16;

  // zero the cross-dispatch accumulators (workspace is poisoned)
  {
    int idx = bid*256 + tid;          // 0..57343 == 896*64-1 exactly
    part[idx] = 0.f;
    if (idx < 896) csp[idx] = 0.f;
    if (idx < 384) cnt[idx] = 0u;
  }

  // Mt = 0.125 * Wk^T Wq  (Wk->Wl, Wq->Mt_l, then overwrite Mt_l)
  stageN(Wl,   Wk, 64, sr, sc);
  stageN(Mt_l, Wq, 64, sr, sc);
  __syncthreads();
  {
    int d = tid >> 2, e0 = (tid & 3) * 16;
    float a[16];
    #pragma unroll
    for (int j = 0; j < 16; j++) a[j] = 0.f;
    for (int dd = 0; dd < 64; dd++) {
      float wkv = Wl[dd][d];
      #pragma unroll
      for (int j = 0; j < 16; j++) a[j] += wkv * Mt_l[dd][e0 + j];
    }
    __syncthreads();                 // all reads of Mt_l(=Wq) done
    #pragma unroll
    for (int j = 0; j < 16; j++) {
      float v = a[j] * 0.125f;
      Mt_l[d][e0 + j] = v;
      if (bid == 0) Mtg[d*64 + e0 + j] = v;
    }
  }

  // slots init (wave owns row r)
  const int r = bid*4 + w;
  const int rb = r / 7, rs = r - rb*7;
  float prev = mu[lane] + __expf(ls[lane]) * noise[(size_t)r*64 + lane];
  slots[(size_t)r*64 + lane] = prev;
  __syncthreads();                   // Mt_l ready

  // q0
  float s1 = prev, s2 = prev*prev;
  #pragma unroll
  for (int m = 1; m < 64; m <<= 1) {
    s1 += __shfl_xor(s1, m, 64);
    s2 += __shfl_xor(s2, m, 64);
  }
  float mean = s1*(1.f/64.f), var = s2*(1.f/64.f) - mean*mean;
  float sv = (prev - mean) * rsqrtf(var + 1e-5f) * lns_w[lane] + lns_b[lane];
  sn2[w][lane] = sv;
  LGKM0();
  float qk = dot_row(Mt_l, lane, sn2[w]);
  float qw = qk * lnw_in[lane];
  float bb = qk * lnb_in[lane];
  #pragma unroll
  for (int m = 1; m < 64; m <<= 1) bb += __shfl_xor(bb, m, 64);
  qkpad[((size_t)rb*16 + rs)*64 + lane] = (f16)qw;
  if (lane == 0) qkaux[(size_t)rb*16 + rs] = bb;
}

// ---------------------------------------------------------------- k_step ----
// 2048 blocks = (b, cx). Attn on one 256-token chunk; atomicAdd partials;
// ticket; LAST block of batch b runs the GRU+MLP(+q) tail for all 7 slots.
__global__ __launch_bounds__(256, 4) void k_step(
    const float* __restrict__ x_in, f16* __restrict__ qkpad,
    float* __restrict__ qkaux, f16* __restrict__ xh,
    float* __restrict__ part, float* __restrict__ csp,
    unsigned* __restrict__ cnt, const float* __restrict__ Mtg,
    float* __restrict__ slots,
    const float* __restrict__ lnw_in, const float* __restrict__ lnb_in,
    const float* __restrict__ lns_w, const float* __restrict__ lns_b,
    const float* __restrict__ lnm_w, const float* __restrict__ lnm_b,
    const float* __restrict__ Wv,
    const float* __restrict__ W_ih, const float* __restrict__ W_hh,
    const float* __restrict__ b_ih, const float* __restrict__ b_hh,
    const float* __restrict__ W1, const float* __restrict__ b1,
    const float* __restrict__ W2, const float* __restrict__ b2,
    int it)
{
  __shared__ __align__(16) float Wl[64][68];
  __shared__ __align__(16) float accb[4][8][64];
  __shared__ float ldsc[4][8];
  __shared__ int lastf;
  __shared__ __align__(16) float updv[7][64];
  __shared__ __align__(16) float u2v [7][64];
  __shared__ __align__(16) float prevv[7][64];
  __shared__ __align__(16) float mlnv[7][64];
  __shared__ __align__(16) float sn2 [7][64];
  __shared__ __align__(16) float hbuf[7][128];

  const int tid = threadIdx.x;
  const int w = tid >> 6, lane = tid & 63, q = lane >> 4, c = lane & 15;
  const int b = blockIdx.x >> 4, cx = blockIdx.x & 15;
  const bool first = (it == 0);

  // ---------------- attn (R8-proven body) ----------------
  f16x8 qkB[2];
  qkB[0] = *(const f16x8*)(qkpad + ((size_t)b*16 + c)*64 + q*8);
  qkB[1] = *(const f16x8*)(qkpad + ((size_t)b*16 + c)*64 + 32 + q*8);
  const float beta = qkaux[(size_t)b*16 + c];

  f16x8 selLo, selHi;
  #pragma unroll
  for (int j = 0; j < 8; j++) {
    selLo[j] = (f16)((( c>>3)    == q && (c&7) == j) ? 1.0f : 0.0f);
    selHi[j] = (f16)(((c>>3) + 2 == q && (c&7) == j) ? 1.0f : 0.0f);
  }

  const f32x4 zero4 = {0.f,0.f,0.f,0.f};
  f32x4 acc[4] = {zero4, zero4, zero4, zero4};
  float csump = 0.f;
  const size_t tok0 = (size_t)b*Nn + (size_t)cx*256 + (size_t)w*64;
  const bool valid = (c < 7);

  if (first) {
    f32x4 nx[4];
    {
      const float* base = x_in + (tok0 + c)*64;
      nx[0] = *(const f32x4*)(base + q*8);
      nx[1] = *(const f32x4*)(base + q*8 + 4);
      nx[2] = *(const f32x4*)(base + 32 + q*8);
      nx[3] = *(const f32x4*)(base + 32 + q*8 + 4);
    }
    #pragma unroll
    for (int t = 0; t < 4; t++) {
      f32x4 xv[4];
      #pragma unroll
      for (int i = 0; i < 4; i++) xv[i] = nx[i];
      if (t < 3) {
        const float* base = x_in + (tok0 + (t+1)*16 + c)*64;
        nx[0] = *(const f32x4*)(base + q*8);
        nx[1] = *(const f32x4*)(base + q*8 + 4);
        nx[2] = *(const f32x4*)(base + 32 + q*8);
        nx[3] = *(const f32x4*)(base + 32 + q*8 + 4);
      }
      float sx  = (xv[0].x+xv[0].y+xv[0].z+xv[0].w) + (xv[1].x+xv[1].y+xv[1].z+xv[1].w)
                + (xv[2].x+xv[2].y+xv[2].z+xv[2].w) + (xv[3].x+xv[3].y+xv[3].z+xv[3].w);
      float sxx = dot4(xv[0],xv[0]) + dot4(xv[1],xv[1])
                + dot4(xv[2],xv[2]) + dot4(xv[3],xv[3]);
      sx  += __shfl_xor(sx, 16, 64);  sx  += __shfl_xor(sx, 32, 64);
      sxx += __shfl_xor(sxx, 16, 64); sxx += __shfl_xor(sxx, 32, 64);
      float mean = sx*(1.f/64.f);
      float rstd = rsqrtf(sxx*(1.f/64.f) - mean*mean + 1e-5f);
      float mr2 = mean * rstd;
      f16x8 xf0, xf1;
      #pragma unroll
      for (int j = 0; j < 4; j++) {
        xf0[j]   = (f16)(xv[0][j]*rstd - mr2);
        xf0[4+j] = (f16)(xv[1][j]*rstd - mr2);
        xf1[j]   = (f16)(xv[2][j]*rstd - mr2);
        xf1[4+j] = (f16)(xv[3][j]*rstd - mr2);
      }
      f16* xo = xh + (tok0 + t*16 + c)*64;
      *(f16x8*)(xo + q*8)      = xf0;
      *(f16x8*)(xo + 32 + q*8) = xf1;
      tile_common(xf0, xf1, qkB, beta, selLo, selHi, valid, acc, csump);
    }
  } else {
    f16x8 L0[4], L1[4];
    #pragma unroll
    for (int t = 0; t < 4; t++) {
      const f16* base = xh + (tok0 + t*16 + c)*64;
      L0[t] = *(const f16x8*)(base + q*8);
      L1[t] = *(const f16x8*)(base + 32 + q*8);
    }
    #pragma unroll
    for (int t = 0; t < 4; t++)
      tile_common(L0[t], L1[t], qkB, beta, selLo, selHi, valid, acc, csump);
  }

  csump += __shfl_xor(csump, 16, 64); csump += __shfl_xor(csump, 32, 64);
  if (q == 0 && c < 7) ldsc[w][c] = csump;
  if (q < 2) {
    #pragma unroll
    for (int nb = 0; nb < 4; nb++)
      #pragma unroll
      for (int rr = 0; rr < 4; rr++)
        accb[w][q*4 + rr][nb*16 + c] = acc[nb][rr];
  }
  __syncthreads();
  for (int rr = tid; rr < 448; rr += 256) {
    int row = rr >> 6, dd = rr & 63;
    float v = accb[0][row][dd] + accb[1][row][dd]
            + accb[2][row][dd] + accb[3][row][dd];
    atomicAdd(&part[(size_t)(b*7 + row)*64 + dd], v);
  }
  if (tid < 7) {
    atomicAdd(&csp[b*7 + tid],
              ldsc[0][tid] + ldsc[1][tid] + ldsc[2][tid] + ldsc[3][tid]);
  }

  // ---------------- ticket: last chunk-block of batch b does the GRU -------
  __syncthreads();                  // all this block's adds drained (vmcnt0)
  if (tid == 0) {
    __threadfence();
    unsigned t = __hip_atomic_fetch_add(&cnt[it*128 + b], 1u,
                   __ATOMIC_ACQ_REL, __HIP_MEMORY_SCOPE_AGENT);
    lastf = (t == NCH - 1) ? 1 : 0;
  }
  __syncthreads();
  if (!lastf) return;

  // ---------------- gru tail for batch b (2 rows per wave) -----------------
  const int b7 = b*7;
  const int r0 = w, r1 = w + 4;
  const bool act1 = (r1 < 7);

  float Y0 = atomicExch(&part[(size_t)(b7 + r0)*64 + lane], 0.f);
  float al0 = 0.f;
  if (lane == 0) al0 = atomicExch(&csp[b7 + r0], 0.f);
  al0 = __shfl(al0, 0, 64);
  float up0 = lnw_in[lane]*(Y0/al0) + lnb_in[lane];
  float prev0 = slots[(size_t)(b7 + r0)*64 + lane];
  updv[r0][lane] = up0; prevv[r0][lane] = prev0;

  float prev1 = 0.f;
  if (act1) {
    float Y1 = atomicExch(&part[(size_t)(b7 + r1)*64 + lane], 0.f);
    float al1 = 0.f;
    if (lane == 0) al1 = atomicExch(&csp[b7 + r1], 0.f);
    al1 = __shfl(al1, 0, 64);
    float up1 = lnw_in[lane]*(Y1/al1) + lnb_in[lane];
    prev1 = slots[(size_t)(b7 + r1)*64 + lane];
    updv[r1][lane] = up1; prevv[r1][lane] = prev1;
  }

  stage_chunk(Wl, Wv, 64, tid);
  u2v[r0][lane] = dot_row(Wl, lane, updv[r0]);
  if (act1) u2v[r1][lane] = dot_row(Wl, lane, updv[r1]);
  LGKM0();

  stage_chunk(Wl, W_ih, 64, tid);
  float air0 = b_ih[lane] + dot_row(Wl, lane, u2v[r0]);
  float air1 = act1 ? b_ih[lane] + dot_row(Wl, lane, u2v[r1]) : 0.f;
  stage_chunk(Wl, W_ih + 4096, 64, tid);
  float aiz0 = b_ih[64+lane] + dot_row(Wl, lane, u2v[r0]);
  float aiz1 = act1 ? b_ih[64+lane] + dot_row(Wl, lane, u2v[r1]) : 0.f;
  stage_chunk(Wl, W_ih + 8192, 64, tid);
  float ain0 = b_ih[128+lane] + dot_row(Wl, lane, u2v[r0]);
  float ain1 = act1 ? b_ih[128+lane] + dot_row(Wl, lane, u2v[r1]) : 0.f;
  stage_chunk(Wl, W_hh, 64, tid);
  float ahr0 = b_hh[lane] + dot_row(Wl, lane, prevv[r0]);
  float ahr1 = act1 ? b_hh[lane] + dot_row(Wl, lane, prevv[r1]) : 0.f;
  stage_chunk(Wl, W_hh + 4096, 64, tid);
  float ahz0 = b_hh[64+lane] + dot_row(Wl, lane, prevv[r0]);
  float ahz1 = act1 ? b_hh[64+lane] + dot_row(Wl, lane, prevv[r1]) : 0.f;
  stage_chunk(Wl, W_hh + 8192, 64, tid);
  float ahn0 = b_hh[128+lane] + dot_row(Wl, lane, prevv[r0]);
  float ahn1 = act1 ? b_hh[128+lane] + dot_row(Wl, lane, prevv[r1]) : 0.f;

  float hnew0, hnew1 = 0.f;
  {
    float rg = 1.f/(1.f + __expf(-(air0+ahr0)));
    float zg = 1.f/(1.f + __expf(-(aiz0+ahz0)));
    float ng = tanhf(ain0 + rg*ahn0);
    hnew0 = (1.f - zg)*ng + zg*prev0;
  }
  if (act1) {
    float rg = 1.f/(1.f + __expf(-(air1+ahr1)));
    float zg = 1.f/(1.f + __expf(-(aiz1+ahz1)));
    float ng = tanhf(ain1 + rg*ahn1);
    hnew1 = (1.f - zg)*ng + zg*prev1;
  }

  // LN(mlp) per row
  {
    float s1 = hnew0, s2 = hnew0*hnew0;
    #pragma unroll
    for (int m = 1; m < 64; m <<= 1) {
      s1 += __shfl_xor(s1, m, 64);
      s2 += __shfl_xor(s2, m, 64);
    }
    float mean = s1*(1.f/64.f), var = s2*(1.f/64.f) - mean*mean;
    mlnv[r0][lane] = (hnew0 - mean) * rsqrtf(var + 1e-5f) * lnm_w[lane] + lnm_b[lane];
  }
  if (act1) {
    float s1 = hnew1, s2 = hnew1*hnew1;
    #pragma unroll
    for (int m = 1; m < 64; m <<= 1) {
      s1 += __shfl_xor(s1, m, 64);
      s2 += __shfl_xor(s2, m, 64);
    }
    float mean = s1*(1.f/64.f), var = s2*(1.f/64.f) - mean*mean;
    mlnv[r1][lane] = (hnew1 - mean) * rsqrtf(var + 1e-5f) * lnm_w[lane] + lnm_b[lane];
  }

  stage_chunk(Wl, W1, 64, tid);
  float h00 = fmaxf(b1[lane] + dot_row(Wl, lane, mlnv[r0]), 0.f);
  float h01 = act1 ? fmaxf(b1[lane] + dot_row(Wl, lane, mlnv[r1]), 0.f) : 0.f;
  stage_chunk(Wl, W1 + 4096, 64, tid);
  float h10 = fmaxf(b1[64+lane] + dot_row(Wl, lane, mlnv[r0]), 0.f);
  float h11 = act1 ? fmaxf(b1[64+lane] + dot_row(Wl, lane, mlnv[r1]), 0.f) : 0.f;
  hbuf[r0][lane] = h00; hbuf[r0][64+lane] = h10;
  if (act1) { hbuf[r1][lane] = h01; hbuf[r1][64+lane] = h11; }
  LGKM0();

  stage_chunk(Wl, W2, 128, tid);
  float out0 = hnew0 + b2[lane] + dot_row(Wl, lane, hbuf[r0]);
  float out1 = act1 ? hnew1 + b2[lane] + dot_row(Wl, lane, hbuf[r1]) : 0.f;
  stage_chunk(Wl, W2 + 64, 128, tid);
  out0 += dot_row(Wl, lane, hbuf[r0] + 64);
  if (act1) out1 += dot_row(Wl, lane, hbuf[r1] + 64);

  slots[(size_t)(b7 + r0)*64 + lane] = out0;
  if (act1) slots[(size_t)(b7 + r1)*64 + lane] = out1;

  if (it < 2) {
    // q for next iteration
    {
      float s1 = out0, s2 = out0*out0;
      #pragma unroll
      for (int m = 1; m < 64; m <<= 1) {
        s1 += __shfl_xor(s1, m, 64);
        s2 += __shfl_xor(s2, m, 64);
      }
      float mean = s1*(1.f/64.f), var = s2*(1.f/64.f) - mean*mean;
      sn2[r0][lane] = (out0 - mean) * rsqrtf(var + 1e-5f) * lns_w[lane] + lns_b[lane];
    }
    if (act1) {
      float s1 = out1, s2 = out1*out1;
      #pragma unroll
      for (int m = 1; m < 64; m <<= 1) {
        s1 += __shfl_xor(s1, m, 64);
        s2 += __shfl_xor(s2, m, 64);
      }
      float mean = s1*(1.f/64.f), var = s2*(1.f/64.f) - mean*mean;
      sn2[r1][lane] = (out1 - mean) * rsqrtf(var + 1e-5f) * lns_w[lane] + lns_b[lane];
    }
    stage_chunk(Wl, Mtg, 64, tid);
    {
      float qk = dot_row(Wl, lane, sn2[r0]);
      float qw = qk * lnw_in[lane];
      float bb = qk * lnb_in[lane];
      #pragma unroll
      for (int m = 1; m < 64; m <<= 1) bb += __shfl_xor(bb, m, 64);
      qkpad[((size_t)b*16 + r0)*64 + lane] = (f16)qw;
      if (lane == 0) qkaux[(size_t)b*16 + r0] = bb;
    }
    if (act1) {
      float qk = dot_row(Wl, lane, sn2[r1]);
      float qw = qk * lnw_in[lane];
      float bb = qk * lnb_in[lane];
      #pragma unroll
      for (int m = 1; m < 64; m <<= 1) bb += __shfl_xor(bb, m, 64);
      qkpad[((size_t)b*16 + r1)*64 + lane] = (f16)qw;
      if (lane == 0) qkaux[(size_t)b*16 + r1] = bb;
    }
  }
}

// ----------------------------------------------------------- kernel_launch --
extern "C" void kernel_launch(void* const* d_in, const int* in_sizes, int n_in,
                              void* d_out, int out_size, void* d_ws, size_t ws_size,
                              hipStream_t stream) {
  const float* inputs  = (const float*)d_in[0];
  const float* noise   = (const float*)d_in[1];
  const float* ln_in_w = (const float*)d_in[2];
  const float* ln_in_b = (const float*)d_in[3];
  const float* ln_sl_w = (const float*)d_in[4];
  const float* ln_sl_b = (const float*)d_in[5];
  const float* ln_ml_w = (const float*)d_in[6];
  const float* ln_ml_b = (const float*)d_in[7];
  const float* mu   = (const float*)d_in[8];
  const float* ls   = (const float*)d_in[9];
  const float* Wq   = (const float*)d_in[10];
  const float* Wk   = (const float*)d_in[11];
  const float* Wv   = (const float*)d_in[12];
  const float* W_ih = (const float*)d_in[13];
  const float* W_hh = (const float*)d_in[14];
  const float* b_ih = (const float*)d_in[15];
  const float* b_hh = (const float*)d_in[16];
  const float* W1 = (const float*)d_in[17];
  const float* b1 = (const float*)d_in[18];
  const float* W2 = (const float*)d_in[19];
  const float* b2 = (const float*)d_in[20];

  float* slots = (float*)d_out;

  // workspace layout (bytes):
  // Mtg  f32 [64][64]        @ 0        (16,384)
  // cnt  u32 [3*128]         @ 16384    (1,536; padded to 2,048)
  // part f32 [896][64]       @ 18432    (229,376)  atomic accumulator
  // csp  f32 [896]           @ 247808   (3,584)    atomic accumulator
  // qkpad f16 [128][16][64]  @ 251392   (262,144)
  // qkaux f32 [128][16]      @ 513536   (8,192)
  // xh   f16 [128][4096][64] @ 521728   (67,108,864)
  const size_t MT_OFF   = 0;
  const size_t CNT_OFF  = 16384;
  const size_t PART_OFF = 18432;
  const size_t CSP_OFF  = PART_OFF + 229376;
  const size_t QK_OFF   = CSP_OFF + 3584;
  const size_t QA_OFF   = QK_OFF + 262144;
  const size_t XH_OFF   = QA_OFF + 8192;
  const size_t NEED     = XH_OFF + 67108864;
  if (ws_size < NEED) return;

  char* ws = (char*)d_ws;
  float*    Mtg   = (float*)(ws + MT_OFF);
  unsigned* cnt   = (unsigned*)(ws + CNT_OFF);
  float*    part  = (float*)(ws + PART_OFF);
  float*    csp   = (float*)(ws + CSP_OFF);
  f16*      qkpad = (f16*)(ws + QK_OFF);
  float*    qkaux = (float*)(ws + QA_OFF);
  f16*      xh    = (f16*)(ws + XH_OFF);

  k_pre<<<224, 256, 0, stream>>>(noise, mu, ls, Wq, Wk,
                                 ln_in_w, ln_in_b, ln_sl_w, ln_sl_b,
                                 slots, qkpad, qkaux, Mtg, part, csp, cnt);
  for (int it = 0; it < 3; it++) {
    k_step<<<2048, 256, 0, stream>>>(inputs, qkpad, qkaux, xh, part, csp,
                                     cnt, Mtg, slots,
                                     ln_in_w, ln_in_b, ln_sl_w, ln_sl_b,
                                     ln_ml_w, ln_ml_b, Wv, W_ih, W_hh,
                                     b_ih, b_hh, W1, b1, W2, b2, it);
  }
}

// Round 10
// 431.016 us; speedup vs baseline: 3.8529x; 3.8529x over previous
//
#include <hip/hip_runtime.h>

// SlotAttention MI355X (gfx950), round 16 = round 15 RESUBMIT (infra failure:
// "container failed twice" = bench never ran; kernel audited deadlock-free:
// all barriers block-uniform, no spins/atomics/cross-block deps, 85KB LDS <
// 130KB proven-launchable, 1024 thr = HW max).
// Structure: ONE dispatch, one block per batch.
//   128 blocks x 1024 thr (16 waves); block b owns batch b for ALL 3 iters.
//   - attn: wave wv handles tokens [wv*256,(wv+1)*256) (16 tiles of 16);
//     partials reduced in LDS accb[16][8][64] -- no cross-block anything.
//   - gru: waves 0-6 own slots; weights staged 64x64 into LDS (1024-thr);
//     prev slots + q vectors (qkw_l/beta_l) stay in regs/LDS across iters.
//   - xh (fp16 LN'd x) written it0 / read it1,2 by the SAME wave (global ws).
//   - Mt = 0.125*Wk^T*Wq computed once per block into resident Mt_l LDS.
// No atomics, no grid sync, no memset, plain <<<>>> -- graph-capture-safe.
// Workspace = xh only (67MB).

#define Nn 4096

typedef _Float16 f16;
typedef _Float16 f16x8 __attribute__((ext_vector_type(8)));
typedef _Float16 f16x4 __attribute__((ext_vector_type(4)));
typedef float    f32x4 __attribute__((ext_vector_type(4)));

#define MFMA16(a,b,c) __builtin_amdgcn_mfma_f32_16x16x16f16(a,b,c,0,0,0)
#define MFMA32(a,b,c) __builtin_amdgcn_mfma_f32_16x16x32_f16(a,b,c,0,0,0)
#define LGKM0() asm volatile("s_waitcnt lgkmcnt(0)" ::: "memory")

#if __has_builtin(__builtin_amdgcn_rcpf)
#define RCPF(x) __builtin_amdgcn_rcpf(x)
#else
#define RCPF(x) (1.0f/(x))
#endif

static __device__ __forceinline__ float dot4(f32x4 a, f32x4 b) {
  return a.x*b.x + a.y*b.y + a.z*b.z + a.w*b.w;
}

static __device__ __forceinline__ float dot_row(
    const float (*Wl)[68], int d, const float* v)
{
  float a0 = 0.f, a1 = 0.f;
  #pragma unroll
  for (int jc = 0; jc < 16; jc += 2) {
    a0 += dot4(*(const f32x4*)&Wl[d][jc*4],     *(const f32x4*)(v + jc*4));
    a1 += dot4(*(const f32x4*)&Wl[d][jc*4 + 4], *(const f32x4*)(v + jc*4 + 4));
  }
  return a0 + a1;
}

// 1024-thread 64x64 chunk staging: each thread one f32x4.
static __device__ __forceinline__ void stage1024(
    float (*Wl)[68], const float* __restrict__ src, int stride, int sr, int sc4)
{
  __syncthreads();                 // protect previous consumers of Wl
  *(f32x4*)&Wl[sr][sc4] = *(const f32x4*)(src + (size_t)sr*stride + sc4);
  __syncthreads();
}

// in-wave LayerNorm over 64 lanes
static __device__ __forceinline__ float ln64(
    float v, const float* __restrict__ w, const float* __restrict__ bias, int lane)
{
  float s1 = v, s2 = v*v;
  #pragma unroll
  for (int m = 1; m < 64; m <<= 1) {
    s1 += __shfl_xor(s1, m, 64);
    s2 += __shfl_xor(s2, m, 64);
  }
  float mean = s1*(1.f/64.f), var = s2*(1.f/64.f) - mean*mean;
  return (v - mean) * rsqrtf(var + 1e-5f) * w[lane] + bias[lane];
}

static __device__ __forceinline__ void tile_common(
    f16x8 xf0, f16x8 xf1, const f16x8* qkB, float beta,
    f16x8 selLo, f16x8 selHi, bool valid, f32x4* acc, float& csump)
{
  const f32x4 zero4 = {0.f,0.f,0.f,0.f};
  f32x4 lg = zero4;
  lg = MFMA32(xf0, qkB[0], lg);
  lg = MFMA32(xf1, qkB[1], lg);
  float e[4], sm[4];
  #pragma unroll
  for (int j = 0; j < 4; j++) {
    float L = lg[j] + beta;
    e[j] = valid ? __expf(L) : 0.f;
    sm[j] = e[j];
  }
  #pragma unroll
  for (int m = 1; m < 16; m <<= 1)
    #pragma unroll
    for (int j = 0; j < 4; j++) sm[j] += __shfl_xor(sm[j], m, 64);
  f16x4 pp;
  #pragma unroll
  for (int j = 0; j < 4; j++) {
    float p = valid ? (e[j]*RCPF(sm[j]) + 1e-8f) : 0.f;
    csump += p;
    pp[j] = (f16)p;
  }
  #pragma unroll
  for (int nb = 0; nb < 4; nb++) {
    f32x4 tr = MFMA32(nb < 2 ? xf0 : xf1, (nb & 1) ? selHi : selLo, zero4);
    f16x4 xt; xt.x=(f16)tr.x; xt.y=(f16)tr.y; xt.z=(f16)tr.z; xt.w=(f16)tr.w;
    acc[nb] = MFMA16(pp, xt, acc[nb]);
  }
}

__global__ __launch_bounds__(1024) void k_all(
    const float* __restrict__ x_in, const float* __restrict__ noise,
    const float* __restrict__ lnw_in, const float* __restrict__ lnb_in,
    const float* __restrict__ lns_w, const float* __restrict__ lns_b,
    const float* __restrict__ lnm_w, const float* __restrict__ lnm_b,
    const float* __restrict__ mu, const float* __restrict__ ls,
    const float* __restrict__ Wq, const float* __restrict__ Wk,
    const float* __restrict__ Wv,
    const float* __restrict__ W_ih, const float* __restrict__ W_hh,
    const float* __restrict__ b_ih, const float* __restrict__ b_hh,
    const float* __restrict__ W1, const float* __restrict__ b1,
    const float* __restrict__ W2, const float* __restrict__ b2,
    float* __restrict__ slots_out, f16* __restrict__ xh)
{
  __shared__ __align__(16) float Wl[64][68];      // 17,408  staging
  __shared__ __align__(16) float Mt_l[64][68];    // 17,408  resident Mt
  __shared__ __align__(16) float accb[16][8][64]; // 32,768  attn partials
  __shared__ float ldsc[16][8];                   //    512
  __shared__ float alphas[8];
  __shared__ __align__(16) f16 qkw_l[16][72];     //  2,304  q (f16, padded)
  __shared__ float beta_l[16];
  __shared__ __align__(16) float updv[7][64];
  __shared__ __align__(16) float u2v [7][64];
  __shared__ __align__(16) float prevv[7][64];
  __shared__ __align__(16) float mlnv[7][64];
  __shared__ __align__(16) float sn2 [7][64];
  __shared__ __align__(16) float hbuf[7][128];    // total ~85 KB

  const int b = blockIdx.x, tid = threadIdx.x;
  const int wv = tid >> 6, lane = tid & 63;
  const int q = lane >> 4, c = lane & 15;
  const int sr = tid >> 4, sc4 = (tid & 15) * 4;  // 1024-thr staging coords

  // ---- Mt = 0.125 * Wk^T Wq into resident Mt_l (Wk->Wl, Wq->Mt_l) ----
  *(f32x4*)&Wl[sr][sc4]   = *(const f32x4*)(Wk + sr*64 + sc4);
  *(f32x4*)&Mt_l[sr][sc4] = *(const f32x4*)(Wq + sr*64 + sc4);
  // zero q rows 7..15 + padding while loads land
  for (int i = tid; i < 16*72; i += 1024) ((f16*)qkw_l)[i] = (f16)0.f;
  if (tid >= 7 && tid < 16) beta_l[tid] = 0.f;
  __syncthreads();
  float mtv[4];
  {
    #pragma unroll
    for (int j = 0; j < 4; j++) mtv[j] = 0.f;
    for (int dd = 0; dd < 64; dd++) {
      float wk = Wl[dd][sr];
      const float* wq = &Mt_l[dd][sc4];
      #pragma unroll
      for (int j = 0; j < 4; j++) mtv[j] += wk * wq[j];
    }
  }
  __syncthreads();                  // all reads of Mt_l(=Wq)/Wl(=Wk) done
  #pragma unroll
  for (int j = 0; j < 4; j++) Mt_l[sr][sc4 + j] = mtv[j] * 0.125f;

  // ---- slots init (waves 0..6 own slot rows) ----
  float prev = 0.f;
  if (wv < 7)
    prev = mu[lane] + __expf(ls[lane]) * noise[(size_t)(b*7 + wv)*64 + lane];
  __syncthreads();                  // Mt_l ready

  // ---- q0 ----
  if (wv < 7) {
    float sv = ln64(prev, lns_w, lns_b, lane);
    sn2[wv][lane] = sv;
    LGKM0();
    float qk = dot_row(Mt_l, lane, sn2[wv]);
    float qw = qk * lnw_in[lane];
    float bb = qk * lnb_in[lane];
    #pragma unroll
    for (int m = 1; m < 64; m <<= 1) bb += __shfl_xor(bb, m, 64);
    qkw_l[wv][lane] = (f16)qw;
    if (lane == 0) beta_l[wv] = bb;
  }
  __syncthreads();

  // selector frags (iteration-invariant)
  f16x8 selLo, selHi;
  #pragma unroll
  for (int j = 0; j < 8; j++) {
    selLo[j] = (f16)((( c>>3)    == q && (c&7) == j) ? 1.0f : 0.0f);
    selHi[j] = (f16)(((c>>3) + 2 == q && (c&7) == j) ? 1.0f : 0.0f);
  }
  const bool valid = (c < 7);
  const f32x4 zero4 = {0.f,0.f,0.f,0.f};

  for (int it = 0; it < 3; ++it) {
    // ================= attn: wave wv = tokens [wv*256,(wv+1)*256) ==========
    f16x8 qkB[2];
    qkB[0] = *(const f16x8*)&qkw_l[c][q*8];
    qkB[1] = *(const f16x8*)&qkw_l[c][32 + q*8];
    const float beta = beta_l[c];

    f32x4 acc[4] = {zero4, zero4, zero4, zero4};
    float csump = 0.f;
    const size_t tok0 = (size_t)b*Nn + (size_t)wv*256;

    if (it == 0) {
      // heavy: fp32 x -> LN in-reg -> fp16 xn store + tile math (16 tiles)
      f32x4 nx[4];
      {
        const float* base = x_in + (tok0 + c)*64;
        nx[0] = *(const f32x4*)(base + q*8);
        nx[1] = *(const f32x4*)(base + q*8 + 4);
        nx[2] = *(const f32x4*)(base + 32 + q*8);
        nx[3] = *(const f32x4*)(base + 32 + q*8 + 4);
      }
      for (int t = 0; t < 16; t++) {
        f32x4 xv[4];
        #pragma unroll
        for (int i = 0; i < 4; i++) xv[i] = nx[i];
        if (t < 15) {
          const float* base = x_in + (tok0 + (t+1)*16 + c)*64;
          nx[0] = *(const f32x4*)(base + q*8);
          nx[1] = *(const f32x4*)(base + q*8 + 4);
          nx[2] = *(const f32x4*)(base + 32 + q*8);
          nx[3] = *(const f32x4*)(base + 32 + q*8 + 4);
        }
        float sx  = (xv[0].x+xv[0].y+xv[0].z+xv[0].w) + (xv[1].x+xv[1].y+xv[1].z+xv[1].w)
                  + (xv[2].x+xv[2].y+xv[2].z+xv[2].w) + (xv[3].x+xv[3].y+xv[3].z+xv[3].w);
        float sxx = dot4(xv[0],xv[0]) + dot4(xv[1],xv[1])
                  + dot4(xv[2],xv[2]) + dot4(xv[3],xv[3]);
        sx  += __shfl_xor(sx, 16, 64);  sx  += __shfl_xor(sx, 32, 64);
        sxx += __shfl_xor(sxx, 16, 64); sxx += __shfl_xor(sxx, 32, 64);
        float mean = sx*(1.f/64.f);
        float rstd = rsqrtf(sxx*(1.f/64.f) - mean*mean + 1e-5f);
        float mr2 = mean * rstd;
        f16x8 xf0, xf1;
        #pragma unroll
        for (int j = 0; j < 4; j++) {
          xf0[j]   = (f16)(xv[0][j]*rstd - mr2);
          xf0[4+j] = (f16)(xv[1][j]*rstd - mr2);
          xf1[j]   = (f16)(xv[2][j]*rstd - mr2);
          xf1[4+j] = (f16)(xv[3][j]*rstd - mr2);
        }
        f16* xo = xh + (tok0 + t*16 + c)*64;
        *(f16x8*)(xo + q*8)      = xf0;
        *(f16x8*)(xo + 32 + q*8) = xf1;
        tile_common(xf0, xf1, qkB, beta, selLo, selHi, valid, acc, csump);
      }
    } else {
      // light: read fp16 xn, groups of 4 preloaded tiles
      for (int g = 0; g < 4; g++) {
        f16x8 L0[4], L1[4];
        #pragma unroll
        for (int tt = 0; tt < 4; tt++) {
          const f16* base = xh + (tok0 + (g*4 + tt)*16 + c)*64;
          L0[tt] = *(const f16x8*)(base + q*8);
          L1[tt] = *(const f16x8*)(base + 32 + q*8);
        }
        #pragma unroll
        for (int tt = 0; tt < 4; tt++)
          tile_common(L0[tt], L1[tt], qkB, beta, selLo, selHi, valid, acc, csump);
      }
    }

    csump += __shfl_xor(csump, 16, 64); csump += __shfl_xor(csump, 32, 64);
    if (q == 0 && c < 7) ldsc[wv][c] = csump;
    if (q < 2) {
      #pragma unroll
      for (int nb = 0; nb < 4; nb++)
        #pragma unroll
        for (int rr = 0; rr < 4; rr++)
          accb[wv][q*4 + rr][nb*16 + c] = acc[nb][rr];
    }
    if (wv < 7) prevv[wv][lane] = prev;
    __syncthreads();

    // ---- in-block reduction over 16 waves ----
    if (tid < 7) {
      float a = 0.f;
      #pragma unroll
      for (int w2 = 0; w2 < 16; w2++) a += ldsc[w2][tid];
      alphas[tid] = a;
    }
    __syncthreads();
    if (tid < 448) {
      int row = tid >> 6, d = tid & 63;
      float Y = 0.f;
      #pragma unroll
      for (int w2 = 0; w2 < 16; w2++) Y += accb[w2][row][d];
      updv[row][d] = lnw_in[d]*(Y / alphas[row]) + lnb_in[d];
    }
    // (stage1024's leading __syncthreads makes updv visible)

    // ================= gru (waves 0..6 compute; all stage) =================
    stage1024(Wl, Wv, 64, sr, sc4);
    if (wv < 7) { u2v[wv][lane] = dot_row(Wl, lane, updv[wv]); }

    stage1024(Wl, W_ih,        64, sr, sc4);
    float air = 0.f, aiz = 0.f, ain = 0.f, ahr = 0.f, ahz = 0.f, ahn = 0.f;
    if (wv < 7) air = b_ih[lane]     + dot_row(Wl, lane, u2v[wv]);
    stage1024(Wl, W_ih + 4096, 64, sr, sc4);
    if (wv < 7) aiz = b_ih[64+lane]  + dot_row(Wl, lane, u2v[wv]);
    stage1024(Wl, W_ih + 8192, 64, sr, sc4);
    if (wv < 7) ain = b_ih[128+lane] + dot_row(Wl, lane, u2v[wv]);
    stage1024(Wl, W_hh,        64, sr, sc4);
    if (wv < 7) ahr = b_hh[lane]     + dot_row(Wl, lane, prevv[wv]);
    stage1024(Wl, W_hh + 4096, 64, sr, sc4);
    if (wv < 7) ahz = b_hh[64+lane]  + dot_row(Wl, lane, prevv[wv]);
    stage1024(Wl, W_hh + 8192, 64, sr, sc4);
    if (wv < 7) ahn = b_hh[128+lane] + dot_row(Wl, lane, prevv[wv]);

    float hnew = 0.f;
    if (wv < 7) {
      float rg = 1.f/(1.f + __expf(-(air+ahr)));
      float zg = 1.f/(1.f + __expf(-(aiz+ahz)));
      float ng = tanhf(ain + rg*ahn);
      hnew = (1.f - zg)*ng + zg*prev;
      mlnv[wv][lane] = ln64(hnew, lnm_w, lnm_b, lane);
    }

    stage1024(Wl, W1,        64, sr, sc4);
    float h0 = 0.f, h1 = 0.f;
    if (wv < 7) h0 = fmaxf(b1[lane]    + dot_row(Wl, lane, mlnv[wv]), 0.f);
    stage1024(Wl, W1 + 4096, 64, sr, sc4);
    if (wv < 7) {
      h1 = fmaxf(b1[64+lane] + dot_row(Wl, lane, mlnv[wv]), 0.f);
      hbuf[wv][lane] = h0; hbuf[wv][64+lane] = h1;
    }
    stage1024(Wl, W2,      128, sr, sc4);
    float out = 0.f;
    if (wv < 7) out = hnew + b2[lane] + dot_row(Wl, lane, hbuf[wv]);
    stage1024(Wl, W2 + 64, 128, sr, sc4);
    if (wv < 7) {
      out += dot_row(Wl, lane, hbuf[wv] + 64);
      prev = out;
    }

    if (it == 2) {
      if (wv < 7) slots_out[(size_t)(b*7 + wv)*64 + lane] = out;
    } else {
      if (wv < 7) {
        float sv = ln64(out, lns_w, lns_b, lane);
        sn2[wv][lane] = sv;
        LGKM0();
        float qk = dot_row(Mt_l, lane, sn2[wv]);
        float qw = qk * lnw_in[lane];
        float bb = qk * lnb_in[lane];
        #pragma unroll
        for (int m = 1; m < 64; m <<= 1) bb += __shfl_xor(bb, m, 64);
        qkw_l[wv][lane] = (f16)qw;
        if (lane == 0) beta_l[wv] = bb;
      }
      __syncthreads();              // q visible to all waves for next attn
    }
  }
}

// ----------------------------------------------------------- kernel_launch --
extern "C" void kernel_launch(void* const* d_in, const int* in_sizes, int n_in,
                              void* d_out, int out_size, void* d_ws, size_t ws_size,
                              hipStream_t stream) {
  const float* inputs  = (const float*)d_in[0];
  const float* noise   = (const float*)d_in[1];
  const float* ln_in_w = (const float*)d_in[2];
  const float* ln_in_b = (const float*)d_in[3];
  const float* ln_sl_w = (const float*)d_in[4];
  const float* ln_sl_b = (const float*)d_in[5];
  const float* ln_ml_w = (const float*)d_in[6];
  const float* ln_ml_b = (const float*)d_in[7];
  const float* mu   = (const float*)d_in[8];
  const float* ls   = (const float*)d_in[9];
  const float* Wq   = (const float*)d_in[10];
  const float* Wk   = (const float*)d_in[11];
  const float* Wv   = (const float*)d_in[12];
  const float* W_ih = (const float*)d_in[13];
  const float* W_hh = (const float*)d_in[14];
  const float* b_ih = (const float*)d_in[15];
  const float* b_hh = (const float*)d_in[16];
  const float* W1 = (const float*)d_in[17];
  const float* b1 = (const float*)d_in[18];
  const float* W2 = (const float*)d_in[19];
  const float* b2 = (const float*)d_in[20];

  float* slots = (float*)d_out;

  // workspace: xh f16 [128][4096][64] only
  const size_t NEED = 67108864;
  if (ws_size < NEED) return;
  f16* xh = (f16*)d_ws;

  k_all<<<128, 1024, 0, stream>>>(
      inputs, noise, ln_in_w, ln_in_b, ln_sl_w, ln_sl_b, ln_ml_w, ln_ml_b,
      mu, ls, Wq, Wk, Wv, W_ih, W_hh, b_ih, b_hh, W1, b1, W2, b2,
      slots, xh);
}